// Round 6
// baseline (864.261 us; speedup 1.0000x reference)
//
#include <hip/hip_runtime.h>
#include <hip/hip_bf16.h>

typedef __attribute__((ext_vector_type(8))) short short8;
typedef __attribute__((ext_vector_type(4))) short bfx4;
typedef __attribute__((ext_vector_type(4))) float floatx4;
typedef __attribute__((ext_vector_type(4))) __fp16 h4_t;
typedef __attribute__((ext_vector_type(2))) __fp16 h2_t;
typedef __attribute__((ext_vector_type(8))) __fp16 h8_t;

#define BATCH 4
#define SEQ 2048
#define D_MODEL 1024
#define NH 16
#define HD 64
#define ELEMS 8388608   // B*S*D = 4*2048*1024
#define WELEMS 1048576  // 1024*1024

// fp32 -> bf16 round-to-nearest-even
__device__ __forceinline__ unsigned short f2bf(float f) {
    union { float f; unsigned u; } x; x.f = f;
    unsigned r = x.u + 0x7FFFu + ((x.u >> 16) & 1u);
    return (unsigned short)(r >> 16);
}
__device__ __forceinline__ unsigned short f2h(float f) {
    union { __fp16 h; unsigned short u; } x;
    x.h = (__fp16)f;
    return x.u;
}

#if __has_builtin(__builtin_amdgcn_exp2f)
__device__ __forceinline__ float fexp2(float x) { return __builtin_amdgcn_exp2f(x); }
#else
__device__ __forceinline__ float fexp2(float x) { return exp2f(x); }
#endif

// async global->LDS, 16B per lane; HW dest = wave-uniform base + lane*16
__device__ __forceinline__ void gll16(const void* g, const void* l) {
    __builtin_amdgcn_global_load_lds(
        (const __attribute__((address_space(1))) void*)g,
        (__attribute__((address_space(3))) void*)l,
        16, 0, 0);
}

// ---------------------------------------------------------------------------
// cvt: x (8M), wq|wk|wv (3M, concatenated), wo (1M) fp32 -> bf16
// ---------------------------------------------------------------------------
__global__ __launch_bounds__(256)
void cvt_kernel(const float* __restrict__ x,  const float* __restrict__ wq,
                const float* __restrict__ wk, const float* __restrict__ wv,
                const float* __restrict__ wo,
                unsigned short* __restrict__ xbf,
                unsigned short* __restrict__ wqkv,
                unsigned short* __restrict__ wobf)
{
    size_t idx = ((size_t)blockIdx.x * 256 + threadIdx.x) * 8;
    const float* src; unsigned short* dst; size_t off;
    if (idx < (size_t)ELEMS)                    { src = x;  dst = xbf;             off = idx; }
    else if (idx < (size_t)ELEMS + WELEMS)      { src = wq; dst = wqkv;            off = idx - ELEMS; }
    else if (idx < (size_t)ELEMS + 2 * WELEMS)  { src = wk; dst = wqkv + WELEMS;   off = idx - ELEMS - WELEMS; }
    else if (idx < (size_t)ELEMS + 3 * WELEMS)  { src = wv; dst = wqkv + 2*WELEMS; off = idx - ELEMS - 2*WELEMS; }
    else                                        { src = wo; dst = wobf;            off = idx - ELEMS - 3*WELEMS; }
    floatx4 a = *(const floatx4*)(src + off);
    floatx4 b = *(const floatx4*)(src + off + 4);
    short8 v;
#pragma unroll
    for (int d = 0; d < 4; d++) { v[d] = (short)f2bf(a[d]); v[4+d] = (short)f2bf(b[d]); }
    *(short8*)(dst + off) = v;
}

// ---------------------------------------------------------------------------
// Fast QKV GEMM: A=x_bf [8192,1024], B=wqkv_bf [3072,1024] (NT), both staged
// via global_load_lds with inverse-XOR-swizzled source addressing.
// 128x256 tile, BK=64. Epilogue scatters Q/K/V (z uniform per block).
// ---------------------------------------------------------------------------
__global__ __launch_bounds__(256, 2)
void gemm_qkv2_kernel(const unsigned short* __restrict__ A,
                      const unsigned short* __restrict__ B,
                      unsigned short* __restrict__ Qb,
                      unsigned short* __restrict__ Kb,
                      unsigned short* __restrict__ Vb)
{
    __shared__ __align__(16) unsigned short As[128 * 64];
    __shared__ __align__(16) unsigned short Bs[256 * 64];

    const int t = threadIdx.x;
    const int wave = t >> 6, lane = t & 63;
    const int lm = lane & 15, lq = lane >> 4;
    const int wrow = (wave >> 1) * 64, wcol = (wave & 1) * 128;
    const int m0 = blockIdx.x * 128, n0 = blockIdx.y * 256;
    const int lrow = lane >> 3, lg = lane & 7;
    const int gsw = lg ^ lrow;

    floatx4 acc[4][8] = {};

    for (int k0 = 0; k0 < 1024; k0 += 64) {
        __syncthreads();
#pragma unroll
        for (int i = 0; i < 4; i++) {
            int rows8 = wave * 32 + i * 8;
            gll16(A + (size_t)(m0 + rows8 + lrow) * 1024 + k0 + gsw * 8, As + rows8 * 64);
        }
#pragma unroll
        for (int i = 0; i < 8; i++) {
            int rows8 = wave * 64 + i * 8;
            gll16(B + (size_t)(n0 + rows8 + lrow) * 1024 + k0 + gsw * 8, Bs + rows8 * 64);
        }
        __syncthreads();

#pragma unroll
        for (int c = 0; c < 2; c++) {
            short8 af[4], bfr[8];
#pragma unroll
            for (int i = 0; i < 4; i++) {
                int ra = wrow + i * 16 + lm;
                int g = c * 4 + lq;
                af[i] = *(const short8*)(As + (ra * 8 + (g ^ (ra & 7))) * 8);
            }
#pragma unroll
            for (int j = 0; j < 8; j++) {
                int rb = wcol + j * 16 + lm;
                int g = c * 4 + lq;
                bfr[j] = *(const short8*)(Bs + (rb * 8 + (g ^ (rb & 7))) * 8);
            }
#pragma unroll
            for (int i = 0; i < 4; i++)
#pragma unroll
                for (int j = 0; j < 8; j++)
                    acc[i][j] = __builtin_amdgcn_mfma_f32_16x16x32_bf16(
                        af[i], bfr[j], acc[i][j], 0, 0, 0);
        }
    }

    const int z = n0 >> 10;   // 0=Q 1=K 2=V, uniform per block
#pragma unroll
    for (int i = 0; i < 4; i++)
#pragma unroll
        for (int j = 0; j < 8; j++)
#pragma unroll
            for (int r = 0; r < 4; r++) {
                int gm = m0 + wrow + i * 16 + lq * 4 + r;
                int gn = n0 + wcol + j * 16 + lm;
                int nl = gn & 1023, h = nl >> 6, d = nl & 63;
                int b = gm >> 11, s = gm & 2047;
                float v = acc[i][j][r];
                size_t bh = (size_t)(b * NH + h);
                if (z == 0)      Qb[(bh * SEQ + s) * HD + d] = f2bf(v);
                else if (z == 1) Kb[(bh * SEQ + s) * HD + d] = f2bf(v);
                else             Vb[(bh * HD + d) * SEQ + s] = f2h(v);
            }
}

// ---------------------------------------------------------------------------
// Fast output projection: A=Ob bf16 [8192,1024], B=wo_bf [1024,1024] -> fp32
// ---------------------------------------------------------------------------
__global__ __launch_bounds__(256, 2)
void gemm_out2_kernel(const unsigned short* __restrict__ A,
                      const unsigned short* __restrict__ B,
                      float* __restrict__ Out)
{
    __shared__ __align__(16) unsigned short As[128 * 64];
    __shared__ __align__(16) unsigned short Bs[256 * 64];

    const int t = threadIdx.x;
    const int wave = t >> 6, lane = t & 63;
    const int lm = lane & 15, lq = lane >> 4;
    const int wrow = (wave >> 1) * 64, wcol = (wave & 1) * 128;
    const int m0 = blockIdx.x * 128, n0 = blockIdx.y * 256;
    const int lrow = lane >> 3, lg = lane & 7;
    const int gsw = lg ^ lrow;

    floatx4 acc[4][8] = {};

    for (int k0 = 0; k0 < 1024; k0 += 64) {
        __syncthreads();
#pragma unroll
        for (int i = 0; i < 4; i++) {
            int rows8 = wave * 32 + i * 8;
            gll16(A + (size_t)(m0 + rows8 + lrow) * 1024 + k0 + gsw * 8, As + rows8 * 64);
        }
#pragma unroll
        for (int i = 0; i < 8; i++) {
            int rows8 = wave * 64 + i * 8;
            gll16(B + (size_t)(n0 + rows8 + lrow) * 1024 + k0 + gsw * 8, Bs + rows8 * 64);
        }
        __syncthreads();

#pragma unroll
        for (int c = 0; c < 2; c++) {
            short8 af[4], bfr[8];
#pragma unroll
            for (int i = 0; i < 4; i++) {
                int ra = wrow + i * 16 + lm;
                int g = c * 4 + lq;
                af[i] = *(const short8*)(As + (ra * 8 + (g ^ (ra & 7))) * 8);
            }
#pragma unroll
            for (int j = 0; j < 8; j++) {
                int rb = wcol + j * 16 + lm;
                int g = c * 4 + lq;
                bfr[j] = *(const short8*)(Bs + (rb * 8 + (g ^ (rb & 7))) * 8);
            }
#pragma unroll
            for (int i = 0; i < 4; i++)
#pragma unroll
                for (int j = 0; j < 8; j++)
                    acc[i][j] = __builtin_amdgcn_mfma_f32_16x16x32_bf16(
                        af[i], bfr[j], acc[i][j], 0, 0, 0);
        }
    }

#pragma unroll
    for (int i = 0; i < 4; i++)
#pragma unroll
        for (int j = 0; j < 8; j++)
#pragma unroll
            for (int r = 0; r < 4; r++) {
                int gm = m0 + wrow + i * 16 + lq * 4 + r;
                int gn = n0 + wcol + j * 16 + lm;
                Out[(size_t)gm * D_MODEL + gn] = acc[i][j][r];
            }
}

// ---------------------------------------------------------------------------
// Flash attention v3: balanced paired q-tiles (j, 31-j) -> uniform 17
// compute-units/block, shared K/V staging, no-max softmax (m=0; shift-
// invariant normalization; masked fill -3.2e10 -> exp2 == 0 exactly),
// deferred l-reduction. Inverted mask (keep kj > qi), scale in exponent.
// Q,K bf16 [b,h,s,d]; V f16 [b,h,d,s]; O bf16 [b,s,1024].
// Row 2047 (l=0 -> NaN) fixed by row2047_kernel afterwards.
// ---------------------------------------------------------------------------
__global__ __launch_bounds__(256, 4)
void attn3_kernel(const unsigned short* __restrict__ Q,
                  const unsigned short* __restrict__ K,
                  const unsigned short* __restrict__ V,
                  unsigned short* __restrict__ O)
{
    __shared__ __align__(16) unsigned short Ks[128 * 64];  // [key][d] swizzled bf16
    __shared__ __align__(16) unsigned short Vs[64 * 128];  // [d][key] swizzled f16

    const int t = threadIdx.x;
    const int wave = t >> 6, lane = t & 63;
    const int lm = lane & 15, lq = lane >> 4;
    const int bh = blockIdx.y;
    const int jlo = blockIdx.x, jhi = 31 - jlo;
    const int qlo = jlo * 64 + wave * 16 + lm;
    const int qhi = jhi * 64 + wave * 16 + lm;

    const unsigned short* Qh = Q + (size_t)bh * SEQ * HD;
    const unsigned short* Kh = K + (size_t)bh * SEQ * HD;
    const unsigned short* Vh = V + (size_t)bh * HD * SEQ;  // [d][s]

    short8 bq_lo[2], bq_hi[2];
    bq_lo[0] = *(const short8*)(Qh + (size_t)qlo * HD + lq * 8);
    bq_lo[1] = *(const short8*)(Qh + (size_t)qlo * HD + 32 + lq * 8);
    bq_hi[0] = *(const short8*)(Qh + (size_t)qhi * HD + lq * 8);
    bq_hi[1] = *(const short8*)(Qh + (size_t)qhi * HD + 32 + lq * 8);

    floatx4 acc_lo[4] = {}, acc_hi[4] = {};
    float l_lo = 0.f, l_hi = 0.f;
    const float kA = 0.04508422002778011f;  // log2(e)/32

    const int lrow = lane >> 3, lg = lane & 7;
    const int kt_min = jlo >> 1;
    const int kthi_min = 15 - kt_min;

    // process one q-tile against the currently staged 128-key tile
    auto process_q = [&](int qi, const short8* bq, floatx4* acc, float& l_acc,
                         bool domask, int kt) {
        floatx4 sv[8];
#pragma unroll
        for (int jt = 0; jt < 8; jt++) {
            floatx4 sc = {};
#pragma unroll
            for (int c = 0; c < 2; c++) {
                int row = jt * 16 + lm;
                int g = c * 4 + lq;
                short8 kf = *(const short8*)(Ks + (row * 8 + (g ^ (row & 7))) * 8);
                sc = __builtin_amdgcn_mfma_f32_16x16x32_bf16(kf, bq[c], sc, 0, 0, 0);
            }
            sv[jt] = sc;
        }
        if (domask) {
#pragma unroll
            for (int jt = 0; jt < 8; jt++)
#pragma unroll
                for (int r = 0; r < 4; r++) {
                    int kj = kt * 128 + jt * 16 + lq * 4 + r;
                    if (!(kj > qi)) sv[jt][r] = -3.2e10f;
                }
        }
        float rs = 0.f;
#pragma unroll
        for (int jt = 0; jt < 8; jt++)
#pragma unroll
            for (int r = 0; r < 4; r++) {
                float p = fexp2(sv[jt][r] * kA);
                sv[jt][r] = p;
                rs += p;
            }
        l_acc += rs;
#pragma unroll
        for (int jt = 0; jt < 8; jt++) {
            h2_t p01 = __builtin_amdgcn_cvt_pkrtz(sv[jt][0], sv[jt][1]);
            h2_t p23 = __builtin_amdgcn_cvt_pkrtz(sv[jt][2], sv[jt][3]);
            h4_t pf;
            pf[0] = p01[0]; pf[1] = p01[1]; pf[2] = p23[0]; pf[3] = p23[1];
#pragma unroll
            for (int jd = 0; jd < 4; jd++) {
                int rowv = jd * 16 + lm;
                int g16 = jt * 2 + (lq >> 1);
                int slot = rowv * 16 + (g16 ^ lm);
                h4_t vf = *(const h4_t*)((const __fp16*)Vs + slot * 8 + (lq & 1) * 4);
                acc[jd] = __builtin_amdgcn_mfma_f32_16x16x16f16(vf, pf, acc[jd], 0, 0, 0);
            }
        }
    };

    for (int kt = 15; kt >= kt_min; kt--) {
        __syncthreads();
        // K tile: 128 keys x 64 d
#pragma unroll
        for (int i = 0; i < 4; i++) {
            int rows8 = wave * 32 + i * 8;
            gll16(Kh + (size_t)(kt * 128 + rows8 + lrow) * HD + (lg ^ lrow) * 8,
                  Ks + rows8 * 64);
        }
        // V^T tile: 64 d x 128 keys
#pragma unroll
        for (int i = 0; i < 4; i++) {
            int rows4 = wave * 16 + i * 4;
            int row = rows4 + (lane >> 4);
            int g = (lane & 15) ^ (row & 15);
            gll16(Vh + (size_t)row * SEQ + kt * 128 + g * 8, Vs + rows4 * 128);
        }
        __syncthreads();

        process_q(qlo, bq_lo, acc_lo, l_lo, kt == kt_min, kt);
        if (kt >= kthi_min)
            process_q(qhi, bq_hi, acc_hi, l_hi, kt == kthi_min, kt);
    }

    const int b = bh >> 4, h = bh & 15;
    {
        float l = l_lo;
        l += __shfl_xor(l, 16); l += __shfl_xor(l, 32);
        float inv = 1.0f / l;
#pragma unroll
        for (int jd = 0; jd < 4; jd++) {
            bfx4 o;
#pragma unroll
            for (int r = 0; r < 4; r++) o[r] = (short)f2bf(acc_lo[jd][r] * inv);
            *(bfx4*)(O + (size_t)(b * SEQ + qlo) * D_MODEL + h * HD + jd * 16 + lq * 4) = o;
        }
    }
    {
        float l = l_hi;
        l += __shfl_xor(l, 16); l += __shfl_xor(l, 32);
        float inv = 1.0f / l;
#pragma unroll
        for (int jd = 0; jd < 4; jd++) {
            bfx4 o;
#pragma unroll
            for (int r = 0; r < 4; r++) o[r] = (short)f2bf(acc_hi[jd][r] * inv);
            *(bfx4*)(O + (size_t)(b * SEQ + qhi) * D_MODEL + h * HD + jd * 16 + lq * 4) = o;
        }
    }
}

// ---------------------------------------------------------------------------
// Row 2047 is fully masked -> uniform softmax over ALL keys -> mean of V.
// ---------------------------------------------------------------------------
__global__ __launch_bounds__(256, 2)
void row2047_kernel(const unsigned short* __restrict__ V,
                    unsigned short* __restrict__ O)
{
    __shared__ float red[256];
    const int bh = blockIdx.x;
    const int b = bh >> 4, h = bh & 15;
    const int t = threadIdx.x;
    const int d = t & 63, seg = t >> 6;
    const __fp16* Vh = (const __fp16*)V + (size_t)bh * HD * SEQ + (size_t)d * SEQ + seg * 512;
    float s = 0.f;
    for (int i = 0; i < 512; i += 8) {
        h8_t v = *(const h8_t*)(Vh + i);
#pragma unroll
        for (int j = 0; j < 8; j++) s += (float)v[j];
    }
    red[t] = s;
    __syncthreads();
    if (seg == 0) {
        float tot = red[d] + red[64 + d] + red[128 + d] + red[192 + d];
        O[(size_t)(b * SEQ + 2047) * D_MODEL + h * HD + d] = f2bf(tot * (1.f / 2048.f));
    }
}

// ======================= fallback (ws < 72 MiB) kernels =====================
__global__ __launch_bounds__(256, 2)
void gemm_qkv_kernel(const float* __restrict__ A,
                     const float* __restrict__ W0,
                     const float* __restrict__ W1,
                     const float* __restrict__ W2,
                     unsigned short* __restrict__ O0,
                     unsigned short* __restrict__ O1,
                     unsigned short* __restrict__ O2)
{
    const int K = 1024;
    const float* W;
    unsigned short* Out;
    if (blockIdx.z == 0)      { W = W0; Out = O0; }
    else if (blockIdx.z == 1) { W = W1; Out = O1; }
    else                      { W = W2; Out = O2; }

    __shared__ __align__(16) unsigned short As[128 * 64];
    __shared__ __align__(16) unsigned short Bs[128 * 64];

    const int t = threadIdx.x;
    const int wave = t >> 6, lane = t & 63;
    const int lm = lane & 15, lq = lane >> 4;
    const int wrow = (wave >> 1) * 64, wcol = (wave & 1) * 64;
    const int m0 = blockIdx.x * 128, n0 = blockIdx.y * 128;

    floatx4 acc[4][4] = {};

    for (int k0 = 0; k0 < K; k0 += 64) {
        __syncthreads();
#pragma unroll
        for (int rr = 0; rr < 4; rr++) {
            int p = rr * 256 + t;
            int row = p >> 3, g = p & 7;
            const float* pa = A + (size_t)(m0 + row) * K + k0 + g * 8;
            const float* pw = W + (size_t)(n0 + row) * K + k0 + g * 8;
            floatx4 a0 = *(const floatx4*)pa, a1 = *(const floatx4*)(pa + 4);
            floatx4 w0 = *(const floatx4*)pw, w1 = *(const floatx4*)(pw + 4);
            short8 va, vb;
#pragma unroll
            for (int d = 0; d < 4; d++) {
                va[d]     = (short)f2bf(a0[d]);
                va[4 + d] = (short)f2bf(a1[d]);
                vb[d]     = (short)f2bf(w0[d]);
                vb[4 + d] = (short)f2bf(w1[d]);
            }
            int dst = row * 8 + (g ^ (row & 7));
            *(short8*)(As + dst * 8) = va;
            *(short8*)(Bs + dst * 8) = vb;
        }
        __syncthreads();

        short8 af[4][2], bf[4][2];
#pragma unroll
        for (int i = 0; i < 4; i++)
#pragma unroll
            for (int c = 0; c < 2; c++) {
                int ra = wrow + i * 16 + lm;
                int rb = wcol + i * 16 + lm;
                int g = c * 4 + lq;
                af[i][c] = *(const short8*)(As + (ra * 8 + (g ^ (ra & 7))) * 8);
                bf[i][c] = *(const short8*)(Bs + (rb * 8 + (g ^ (rb & 7))) * 8);
            }
#pragma unroll
        for (int i = 0; i < 4; i++)
#pragma unroll
            for (int j = 0; j < 4; j++)
#pragma unroll
                for (int c = 0; c < 2; c++)
                    acc[i][j] = __builtin_amdgcn_mfma_f32_16x16x32_bf16(
                        af[i][c], bf[j][c], acc[i][j], 0, 0, 0);
    }

    const int zi = blockIdx.z;
#pragma unroll
    for (int i = 0; i < 4; i++)
#pragma unroll
        for (int j = 0; j < 4; j++)
#pragma unroll
            for (int r = 0; r < 4; r++) {
                int gm = m0 + wrow + i * 16 + lq * 4 + r;
                int gn = n0 + wcol + j * 16 + lm;
                int b = gm >> 11, s = gm & 2047;
                int h = gn >> 6, d = gn & 63;
                if (zi == 2) {
                    Out[((size_t)(b * NH + h) * HD + d) * SEQ + s] = f2h(acc[i][j][r]);
                } else {
                    Out[((size_t)(b * NH + h) * SEQ + s) * HD + d] = f2bf(acc[i][j][r]);
                }
            }
}

__global__ __launch_bounds__(256, 2)
void gemm_out_kernel(const unsigned short* __restrict__ Abf,
                     const float* __restrict__ W,
                     float* __restrict__ Out)
{
    const int K = 1024;
    __shared__ __align__(16) unsigned short As[128 * 64];
    __shared__ __align__(16) unsigned short Bs[128 * 64];

    const int t = threadIdx.x;
    const int wave = t >> 6, lane = t & 63;
    const int lm = lane & 15, lq = lane >> 4;
    const int wrow = (wave >> 1) * 64, wcol = (wave & 1) * 64;
    const int m0 = blockIdx.x * 128, n0 = blockIdx.y * 128;

    floatx4 acc[4][4] = {};

    for (int k0 = 0; k0 < K; k0 += 64) {
        __syncthreads();
#pragma unroll
        for (int rr = 0; rr < 4; rr++) {
            int p = rr * 256 + t;
            int row = p >> 3, g = p & 7;
            short8 va = *(const short8*)(Abf + (size_t)(m0 + row) * K + k0 + g * 8);
            const float* pw = W + (size_t)(n0 + row) * K + k0 + g * 8;
            floatx4 w0 = *(const floatx4*)pw, w1 = *(const floatx4*)(pw + 4);
            short8 vb;
#pragma unroll
            for (int d = 0; d < 4; d++) {
                vb[d]     = (short)f2bf(w0[d]);
                vb[4 + d] = (short)f2bf(w1[d]);
            }
            int dst = row * 8 + (g ^ (row & 7));
            *(short8*)(As + dst * 8) = va;
            *(short8*)(Bs + dst * 8) = vb;
        }
        __syncthreads();

        short8 af[4][2], bf[4][2];
#pragma unroll
        for (int i = 0; i < 4; i++)
#pragma unroll
            for (int c = 0; c < 2; c++) {
                int ra = wrow + i * 16 + lm;
                int rb = wcol + i * 16 + lm;
                int g = c * 4 + lq;
                af[i][c] = *(const short8*)(As + (ra * 8 + (g ^ (ra & 7))) * 8);
                bf[i][c] = *(const short8*)(Bs + (rb * 8 + (g ^ (rb & 7))) * 8);
            }
#pragma unroll
        for (int i = 0; i < 4; i++)
#pragma unroll
            for (int j = 0; j < 4; j++)
#pragma unroll
                for (int c = 0; c < 2; c++)
                    acc[i][j] = __builtin_amdgcn_mfma_f32_16x16x32_bf16(
                        af[i][c], bf[j][c], acc[i][j], 0, 0, 0);
    }

#pragma unroll
    for (int i = 0; i < 4; i++)
#pragma unroll
        for (int j = 0; j < 4; j++)
#pragma unroll
            for (int r = 0; r < 4; r++) {
                int gm = m0 + wrow + i * 16 + lq * 4 + r;
                int gn = n0 + wcol + j * 16 + lm;
                Out[(size_t)gm * D_MODEL + gn] = acc[i][j][r];
            }
}

extern "C" void kernel_launch(void* const* d_in, const int* in_sizes, int n_in,
                              void* d_out, int out_size, void* d_ws, size_t ws_size,
                              hipStream_t stream) {
    const float* x  = (const float*)d_in[0];
    const float* wq = (const float*)d_in[1];
    const float* wk = (const float*)d_in[2];
    const float* wv = (const float*)d_in[3];
    const float* wo = (const float*)d_in[4];

    unsigned short* ws = (unsigned short*)d_ws;
    const bool fast = ws_size >= (size_t)36 * 1024 * 1024 * 2;  // 72 MiB

    if (fast) {
        unsigned short* xbf  = ws;                     // 8M elems; reused as Ob
        unsigned short* wqkv = ws + (size_t)ELEMS;     // 3M
        unsigned short* wobf = ws + (size_t)ELEMS + 3 * WELEMS;  // 1M
        unsigned short* Qb   = ws + (size_t)ELEMS + 4 * WELEMS;  // 8M
        unsigned short* Kb   = Qb + ELEMS;
        unsigned short* Vb   = Kb + ELEMS;
        unsigned short* Ob   = xbf;                    // x_bf dead after QKV GEMM

        cvt_kernel<<<6144, 256, 0, stream>>>(x, wq, wk, wv, wo, xbf, wqkv, wobf);
        gemm_qkv2_kernel<<<dim3(64, 12), 256, 0, stream>>>(xbf, wqkv, Qb, Kb, Vb);
        attn3_kernel<<<dim3(16, BATCH * NH), 256, 0, stream>>>(Qb, Kb, Vb, Ob);
        row2047_kernel<<<BATCH * NH, 256, 0, stream>>>(Vb, Ob);
        gemm_out2_kernel<<<dim3(64, 4), 256, 0, stream>>>(Ob, wobf, (float*)d_out);
    } else {
        unsigned short* Qb = ws;
        unsigned short* Kb = Qb + ELEMS;
        unsigned short* Vb = Kb + ELEMS;
        unsigned short* Ob = Vb + ELEMS;

        gemm_qkv_kernel<<<dim3(64, 8, 3), 256, 0, stream>>>(x, wq, wk, wv, Qb, Kb, Vb);
        attn3_kernel<<<dim3(16, BATCH * NH), 256, 0, stream>>>(Qb, Kb, Vb, Ob);
        row2047_kernel<<<BATCH * NH, 256, 0, stream>>>(Vb, Ob);
        gemm_out_kernel<<<dim3(64, 8), 256, 0, stream>>>(Ob, wo, (float*)d_out);
    }
}

// Round 7
// 788.558 us; speedup vs baseline: 1.0960x; 1.0960x over previous
//
#include <hip/hip_runtime.h>
#include <hip/hip_bf16.h>

typedef __attribute__((ext_vector_type(8))) short short8;
typedef __attribute__((ext_vector_type(4))) short bfx4;
typedef __attribute__((ext_vector_type(4))) float floatx4;
typedef __attribute__((ext_vector_type(4))) __fp16 h4_t;
typedef __attribute__((ext_vector_type(2))) __fp16 h2_t;
typedef __attribute__((ext_vector_type(8))) __fp16 h8_t;

#define BATCH 4
#define SEQ 2048
#define D_MODEL 1024
#define NH 16
#define HD 64
#define ELEMS 8388608   // B*S*D = 4*2048*1024
#define WELEMS 1048576  // 1024*1024

// fp32 -> bf16 round-to-nearest-even
__device__ __forceinline__ unsigned short f2bf(float f) {
    union { float f; unsigned u; } x; x.f = f;
    unsigned r = x.u + 0x7FFFu + ((x.u >> 16) & 1u);
    return (unsigned short)(r >> 16);
}
__device__ __forceinline__ unsigned short f2h(float f) {
    union { __fp16 h; unsigned short u; } x;
    x.h = (__fp16)f;
    return x.u;
}

#if __has_builtin(__builtin_amdgcn_exp2f)
__device__ __forceinline__ float fexp2(float x) { return __builtin_amdgcn_exp2f(x); }
#else
__device__ __forceinline__ float fexp2(float x) { return exp2f(x); }
#endif

// async global->LDS, 16B per lane; HW dest = wave-uniform base + lane*16
__device__ __forceinline__ void gll16(const void* g, const void* l) {
    __builtin_amdgcn_global_load_lds(
        (const __attribute__((address_space(1))) void*)g,
        (__attribute__((address_space(3))) void*)l,
        16, 0, 0);
}

// ---------------------------------------------------------------------------
// cvt: x (8M), wq|wk|wv (3M, concatenated), wo (1M) fp32 -> bf16
// ---------------------------------------------------------------------------
__global__ __launch_bounds__(256)
void cvt_kernel(const float* __restrict__ x,  const float* __restrict__ wq,
                const float* __restrict__ wk, const float* __restrict__ wv,
                const float* __restrict__ wo,
                unsigned short* __restrict__ xbf,
                unsigned short* __restrict__ wqkv,
                unsigned short* __restrict__ wobf)
{
    size_t idx = ((size_t)blockIdx.x * 256 + threadIdx.x) * 8;
    const float* src; unsigned short* dst; size_t off;
    if (idx < (size_t)ELEMS)                    { src = x;  dst = xbf;             off = idx; }
    else if (idx < (size_t)ELEMS + WELEMS)      { src = wq; dst = wqkv;            off = idx - ELEMS; }
    else if (idx < (size_t)ELEMS + 2 * WELEMS)  { src = wk; dst = wqkv + WELEMS;   off = idx - ELEMS - WELEMS; }
    else if (idx < (size_t)ELEMS + 3 * WELEMS)  { src = wv; dst = wqkv + 2*WELEMS; off = idx - ELEMS - 2*WELEMS; }
    else                                        { src = wo; dst = wobf;            off = idx - ELEMS - 3*WELEMS; }
    floatx4 a = *(const floatx4*)(src + off);
    floatx4 b = *(const floatx4*)(src + off + 4);
    short8 v;
#pragma unroll
    for (int d = 0; d < 4; d++) { v[d] = (short)f2bf(a[d]); v[4+d] = (short)f2bf(b[d]); }
    *(short8*)(dst + off) = v;
}

// ---------------------------------------------------------------------------
// Fast QKV GEMM: A=x_bf [8192,1024], B=wqkv_bf [3072,1024] (NT), both staged
// via global_load_lds with inverse-XOR-swizzled source addressing.
// 128x256 tile, BK=64. Epilogue scatters Q/K/V (z uniform per block).
// ---------------------------------------------------------------------------
__global__ __launch_bounds__(256, 2)
void gemm_qkv2_kernel(const unsigned short* __restrict__ A,
                      const unsigned short* __restrict__ B,
                      unsigned short* __restrict__ Qb,
                      unsigned short* __restrict__ Kb,
                      unsigned short* __restrict__ Vb)
{
    __shared__ __align__(16) unsigned short As[128 * 64];
    __shared__ __align__(16) unsigned short Bs[256 * 64];

    const int t = threadIdx.x;
    const int wave = t >> 6, lane = t & 63;
    const int lm = lane & 15, lq = lane >> 4;
    const int wrow = (wave >> 1) * 64, wcol = (wave & 1) * 128;
    const int m0 = blockIdx.x * 128, n0 = blockIdx.y * 256;
    const int lrow = lane >> 3, lg = lane & 7;
    const int gsw = lg ^ lrow;

    floatx4 acc[4][8] = {};

    for (int k0 = 0; k0 < 1024; k0 += 64) {
        __syncthreads();
#pragma unroll
        for (int i = 0; i < 4; i++) {
            int rows8 = wave * 32 + i * 8;
            gll16(A + (size_t)(m0 + rows8 + lrow) * 1024 + k0 + gsw * 8, As + rows8 * 64);
        }
#pragma unroll
        for (int i = 0; i < 8; i++) {
            int rows8 = wave * 64 + i * 8;
            gll16(B + (size_t)(n0 + rows8 + lrow) * 1024 + k0 + gsw * 8, Bs + rows8 * 64);
        }
        __syncthreads();

#pragma unroll
        for (int c = 0; c < 2; c++) {
            short8 af[4], bfr[8];
#pragma unroll
            for (int i = 0; i < 4; i++) {
                int ra = wrow + i * 16 + lm;
                int g = c * 4 + lq;
                af[i] = *(const short8*)(As + (ra * 8 + (g ^ (ra & 7))) * 8);
            }
#pragma unroll
            for (int j = 0; j < 8; j++) {
                int rb = wcol + j * 16 + lm;
                int g = c * 4 + lq;
                bfr[j] = *(const short8*)(Bs + (rb * 8 + (g ^ (rb & 7))) * 8);
            }
#pragma unroll
            for (int i = 0; i < 4; i++)
#pragma unroll
                for (int j = 0; j < 8; j++)
                    acc[i][j] = __builtin_amdgcn_mfma_f32_16x16x32_bf16(
                        af[i], bfr[j], acc[i][j], 0, 0, 0);
        }
    }

    const int z = n0 >> 10;   // 0=Q 1=K 2=V, uniform per block
#pragma unroll
    for (int i = 0; i < 4; i++)
#pragma unroll
        for (int j = 0; j < 8; j++)
#pragma unroll
            for (int r = 0; r < 4; r++) {
                int gm = m0 + wrow + i * 16 + lq * 4 + r;
                int gn = n0 + wcol + j * 16 + lm;
                int nl = gn & 1023, h = nl >> 6, d = nl & 63;
                int b = gm >> 11, s = gm & 2047;
                float v = acc[i][j][r];
                size_t bh = (size_t)(b * NH + h);
                if (z == 0)      Qb[(bh * SEQ + s) * HD + d] = f2bf(v);
                else if (z == 1) Kb[(bh * SEQ + s) * HD + d] = f2bf(v);
                else             Vb[(bh * HD + d) * SEQ + s] = f2h(v);
            }
}

// ---------------------------------------------------------------------------
// Fast output projection: A=Ob bf16 [8192,1024], B=wo_bf [1024,1024] -> fp32
// ---------------------------------------------------------------------------
__global__ __launch_bounds__(256, 2)
void gemm_out2_kernel(const unsigned short* __restrict__ A,
                      const unsigned short* __restrict__ B,
                      float* __restrict__ Out)
{
    __shared__ __align__(16) unsigned short As[128 * 64];
    __shared__ __align__(16) unsigned short Bs[256 * 64];

    const int t = threadIdx.x;
    const int wave = t >> 6, lane = t & 63;
    const int lm = lane & 15, lq = lane >> 4;
    const int wrow = (wave >> 1) * 64, wcol = (wave & 1) * 128;
    const int m0 = blockIdx.x * 128, n0 = blockIdx.y * 256;
    const int lrow = lane >> 3, lg = lane & 7;
    const int gsw = lg ^ lrow;

    floatx4 acc[4][8] = {};

    for (int k0 = 0; k0 < 1024; k0 += 64) {
        __syncthreads();
#pragma unroll
        for (int i = 0; i < 4; i++) {
            int rows8 = wave * 32 + i * 8;
            gll16(A + (size_t)(m0 + rows8 + lrow) * 1024 + k0 + gsw * 8, As + rows8 * 64);
        }
#pragma unroll
        for (int i = 0; i < 8; i++) {
            int rows8 = wave * 64 + i * 8;
            gll16(B + (size_t)(n0 + rows8 + lrow) * 1024 + k0 + gsw * 8, Bs + rows8 * 64);
        }
        __syncthreads();

#pragma unroll
        for (int c = 0; c < 2; c++) {
            short8 af[4], bfr[8];
#pragma unroll
            for (int i = 0; i < 4; i++) {
                int ra = wrow + i * 16 + lm;
                int g = c * 4 + lq;
                af[i] = *(const short8*)(As + (ra * 8 + (g ^ (ra & 7))) * 8);
            }
#pragma unroll
            for (int j = 0; j < 8; j++) {
                int rb = wcol + j * 16 + lm;
                int g = c * 4 + lq;
                bfr[j] = *(const short8*)(Bs + (rb * 8 + (g ^ (rb & 7))) * 8);
            }
#pragma unroll
            for (int i = 0; i < 4; i++)
#pragma unroll
                for (int j = 0; j < 8; j++)
                    acc[i][j] = __builtin_amdgcn_mfma_f32_16x16x32_bf16(
                        af[i], bfr[j], acc[i][j], 0, 0, 0);
        }
    }

#pragma unroll
    for (int i = 0; i < 4; i++)
#pragma unroll
        for (int j = 0; j < 8; j++)
#pragma unroll
            for (int r = 0; r < 4; r++) {
                int gm = m0 + wrow + i * 16 + lq * 4 + r;
                int gn = n0 + wcol + j * 16 + lm;
                Out[(size_t)gm * D_MODEL + gn] = acc[i][j][r];
            }
}

// ---------------------------------------------------------------------------
// Flash attention v4: balanced paired q-tiles (j, 31-j), no-max softmax,
// STREAMED sub-tiles (no sv[8] array, no lambda, no array-pointer args --
// the R6 version spilled acc to scratch via the lambda pointer and thrashed
// HBM at 2.6 GB/dispatch). Per 16-key sub-tile: QK-MFMA -> mask -> exp ->
// pkrtz -> PV-MFMA; transient = one floatx4.
// Q,K bf16 [b,h,s,d]; V f16 [b,h,d,s]; O bf16 [b,s,1024].
// Row 2047 (l=0) fixed by row2047_kernel afterwards.
// ---------------------------------------------------------------------------
#define PROCESS_Q(QI, BQ, ACC, LACC, DOMASK, KT)                               \
    do {                                                                       \
        _Pragma("unroll")                                                      \
        for (int jt = 0; jt < 8; jt++) {                                       \
            floatx4 sc = {};                                                   \
            _Pragma("unroll")                                                  \
            for (int c = 0; c < 2; c++) {                                      \
                int row_ = jt * 16 + lm;                                       \
                int g_ = c * 4 + lq;                                           \
                short8 kf = *(const short8*)(Ks + (row_ * 8 + (g_ ^ (row_ & 7))) * 8); \
                sc = __builtin_amdgcn_mfma_f32_16x16x32_bf16(kf, BQ[c], sc, 0, 0, 0); \
            }                                                                  \
            if (DOMASK) {                                                      \
                _Pragma("unroll")                                              \
                for (int r = 0; r < 4; r++) {                                  \
                    int kj = (KT) * 128 + jt * 16 + lq * 4 + r;                \
                    if (!(kj > (QI))) sc[r] = -3.2e10f;                        \
                }                                                              \
            }                                                                  \
            float p0 = fexp2(sc[0] * kA), p1 = fexp2(sc[1] * kA);              \
            float p2 = fexp2(sc[2] * kA), p3 = fexp2(sc[3] * kA);              \
            LACC += (p0 + p1) + (p2 + p3);                                     \
            h2_t a01 = __builtin_amdgcn_cvt_pkrtz(p0, p1);                     \
            h2_t a23 = __builtin_amdgcn_cvt_pkrtz(p2, p3);                     \
            h4_t pf;                                                           \
            pf[0] = a01[0]; pf[1] = a01[1]; pf[2] = a23[0]; pf[3] = a23[1];    \
            _Pragma("unroll")                                                  \
            for (int jd = 0; jd < 4; jd++) {                                   \
                int rowv_ = jd * 16 + lm;                                      \
                int g16_ = jt * 2 + (lq >> 1);                                 \
                int slot_ = rowv_ * 16 + (g16_ ^ lm);                          \
                h4_t vf = *(const h4_t*)((const __fp16*)Vs + slot_ * 8 + (lq & 1) * 4); \
                ACC[jd] = __builtin_amdgcn_mfma_f32_16x16x16f16(vf, pf, ACC[jd], 0, 0, 0); \
            }                                                                  \
        }                                                                      \
    } while (0)

__global__ __launch_bounds__(256, 4)
void attn4_kernel(const unsigned short* __restrict__ Q,
                  const unsigned short* __restrict__ K,
                  const unsigned short* __restrict__ V,
                  unsigned short* __restrict__ O)
{
    __shared__ __align__(16) unsigned short Ks[128 * 64];  // [key][d] swizzled bf16
    __shared__ __align__(16) unsigned short Vs[64 * 128];  // [d][key] swizzled f16

    const int t = threadIdx.x;
    const int wave = t >> 6, lane = t & 63;
    const int lm = lane & 15, lq = lane >> 4;
    const int bh = blockIdx.y;
    const int jlo = blockIdx.x, jhi = 31 - jlo;
    const int qlo = jlo * 64 + wave * 16 + lm;
    const int qhi = jhi * 64 + wave * 16 + lm;

    const unsigned short* Qh = Q + (size_t)bh * SEQ * HD;
    const unsigned short* Kh = K + (size_t)bh * SEQ * HD;
    const unsigned short* Vh = V + (size_t)bh * HD * SEQ;  // [d][s]

    short8 bq_lo[2], bq_hi[2];
    bq_lo[0] = *(const short8*)(Qh + (size_t)qlo * HD + lq * 8);
    bq_lo[1] = *(const short8*)(Qh + (size_t)qlo * HD + 32 + lq * 8);
    bq_hi[0] = *(const short8*)(Qh + (size_t)qhi * HD + lq * 8);
    bq_hi[1] = *(const short8*)(Qh + (size_t)qhi * HD + 32 + lq * 8);

    floatx4 acc_lo[4] = {}, acc_hi[4] = {};
    float l_lo = 0.f, l_hi = 0.f;
    const float kA = 0.04508422002778011f;  // log2(e)/32

    const int lrow = lane >> 3, lg = lane & 7;
    const int kt_min = jlo >> 1;
    const int kthi_min = 15 - kt_min;

    for (int kt = 15; kt >= kt_min; kt--) {
        __syncthreads();
        // K tile: 128 keys x 64 d
#pragma unroll
        for (int i = 0; i < 4; i++) {
            int rows8 = wave * 32 + i * 8;
            gll16(Kh + (size_t)(kt * 128 + rows8 + lrow) * HD + (lg ^ lrow) * 8,
                  Ks + rows8 * 64);
        }
        // V^T tile: 64 d x 128 keys
#pragma unroll
        for (int i = 0; i < 4; i++) {
            int rows4 = wave * 16 + i * 4;
            int row = rows4 + (lane >> 4);
            int g = (lane & 15) ^ (row & 15);
            gll16(Vh + (size_t)row * SEQ + kt * 128 + g * 8, Vs + rows4 * 128);
        }
        __syncthreads();

        PROCESS_Q(qlo, bq_lo, acc_lo, l_lo, (kt == kt_min), kt);
        if (kt >= kthi_min)
            PROCESS_Q(qhi, bq_hi, acc_hi, l_hi, (kt == kthi_min), kt);
    }

    const int b = bh >> 4, h = bh & 15;
    {
        float l = l_lo;
        l += __shfl_xor(l, 16); l += __shfl_xor(l, 32);
        float inv = 1.0f / l;
#pragma unroll
        for (int jd = 0; jd < 4; jd++) {
            bfx4 o;
#pragma unroll
            for (int r = 0; r < 4; r++) o[r] = (short)f2bf(acc_lo[jd][r] * inv);
            *(bfx4*)(O + (size_t)(b * SEQ + qlo) * D_MODEL + h * HD + jd * 16 + lq * 4) = o;
        }
    }
    {
        float l = l_hi;
        l += __shfl_xor(l, 16); l += __shfl_xor(l, 32);
        float inv = 1.0f / l;
#pragma unroll
        for (int jd = 0; jd < 4; jd++) {
            bfx4 o;
#pragma unroll
            for (int r = 0; r < 4; r++) o[r] = (short)f2bf(acc_hi[jd][r] * inv);
            *(bfx4*)(O + (size_t)(b * SEQ + qhi) * D_MODEL + h * HD + jd * 16 + lq * 4) = o;
        }
    }
}

// ---------------------------------------------------------------------------
// Row 2047 is fully masked -> uniform softmax over ALL keys -> mean of V.
// ---------------------------------------------------------------------------
__global__ __launch_bounds__(256, 2)
void row2047_kernel(const unsigned short* __restrict__ V,
                    unsigned short* __restrict__ O)
{
    __shared__ float red[256];
    const int bh = blockIdx.x;
    const int b = bh >> 4, h = bh & 15;
    const int t = threadIdx.x;
    const int d = t & 63, seg = t >> 6;
    const __fp16* Vh = (const __fp16*)V + (size_t)bh * HD * SEQ + (size_t)d * SEQ + seg * 512;
    float s = 0.f;
    for (int i = 0; i < 512; i += 8) {
        h8_t v = *(const h8_t*)(Vh + i);
#pragma unroll
        for (int j = 0; j < 8; j++) s += (float)v[j];
    }
    red[t] = s;
    __syncthreads();
    if (seg == 0) {
        float tot = red[d] + red[64 + d] + red[128 + d] + red[192 + d];
        O[(size_t)(b * SEQ + 2047) * D_MODEL + h * HD + d] = f2bf(tot * (1.f / 2048.f));
    }
}

// ======================= fallback (ws < 72 MiB) kernels =====================
__global__ __launch_bounds__(256, 2)
void gemm_qkv_kernel(const float* __restrict__ A,
                     const float* __restrict__ W0,
                     const float* __restrict__ W1,
                     const float* __restrict__ W2,
                     unsigned short* __restrict__ O0,
                     unsigned short* __restrict__ O1,
                     unsigned short* __restrict__ O2)
{
    const int K = 1024;
    const float* W;
    unsigned short* Out;
    if (blockIdx.z == 0)      { W = W0; Out = O0; }
    else if (blockIdx.z == 1) { W = W1; Out = O1; }
    else                      { W = W2; Out = O2; }

    __shared__ __align__(16) unsigned short As[128 * 64];
    __shared__ __align__(16) unsigned short Bs[128 * 64];

    const int t = threadIdx.x;
    const int wave = t >> 6, lane = t & 63;
    const int lm = lane & 15, lq = lane >> 4;
    const int wrow = (wave >> 1) * 64, wcol = (wave & 1) * 64;
    const int m0 = blockIdx.x * 128, n0 = blockIdx.y * 128;

    floatx4 acc[4][4] = {};

    for (int k0 = 0; k0 < K; k0 += 64) {
        __syncthreads();
#pragma unroll
        for (int rr = 0; rr < 4; rr++) {
            int p = rr * 256 + t;
            int row = p >> 3, g = p & 7;
            const float* pa = A + (size_t)(m0 + row) * K + k0 + g * 8;
            const float* pw = W + (size_t)(n0 + row) * K + k0 + g * 8;
            floatx4 a0 = *(const floatx4*)pa, a1 = *(const floatx4*)(pa + 4);
            floatx4 w0 = *(const floatx4*)pw, w1 = *(const floatx4*)(pw + 4);
            short8 va, vb;
#pragma unroll
            for (int d = 0; d < 4; d++) {
                va[d]     = (short)f2bf(a0[d]);
                va[4 + d] = (short)f2bf(a1[d]);
                vb[d]     = (short)f2bf(w0[d]);
                vb[4 + d] = (short)f2bf(w1[d]);
            }
            int dst = row * 8 + (g ^ (row & 7));
            *(short8*)(As + dst * 8) = va;
            *(short8*)(Bs + dst * 8) = vb;
        }
        __syncthreads();

        short8 af[4][2], bf[4][2];
#pragma unroll
        for (int i = 0; i < 4; i++)
#pragma unroll
            for (int c = 0; c < 2; c++) {
                int ra = wrow + i * 16 + lm;
                int rb = wcol + i * 16 + lm;
                int g = c * 4 + lq;
                af[i][c] = *(const short8*)(As + (ra * 8 + (g ^ (ra & 7))) * 8);
                bf[i][c] = *(const short8*)(Bs + (rb * 8 + (g ^ (rb & 7))) * 8);
            }
#pragma unroll
        for (int i = 0; i < 4; i++)
#pragma unroll
            for (int j = 0; j < 4; j++)
#pragma unroll
                for (int c = 0; c < 2; c++)
                    acc[i][j] = __builtin_amdgcn_mfma_f32_16x16x32_bf16(
                        af[i][c], bf[j][c], acc[i][j], 0, 0, 0);
    }

    const int zi = blockIdx.z;
#pragma unroll
    for (int i = 0; i < 4; i++)
#pragma unroll
        for (int j = 0; j < 4; j++)
#pragma unroll
            for (int r = 0; r < 4; r++) {
                int gm = m0 + wrow + i * 16 + lq * 4 + r;
                int gn = n0 + wcol + j * 16 + lm;
                int b = gm >> 11, s = gm & 2047;
                int h = gn >> 6, d = gn & 63;
                if (zi == 2) {
                    Out[((size_t)(b * NH + h) * HD + d) * SEQ + s] = f2h(acc[i][j][r]);
                } else {
                    Out[((size_t)(b * NH + h) * SEQ + s) * HD + d] = f2bf(acc[i][j][r]);
                }
            }
}

__global__ __launch_bounds__(256, 2)
void gemm_out_kernel(const unsigned short* __restrict__ Abf,
                     const float* __restrict__ W,
                     float* __restrict__ Out)
{
    const int K = 1024;
    __shared__ __align__(16) unsigned short As[128 * 64];
    __shared__ __align__(16) unsigned short Bs[128 * 64];

    const int t = threadIdx.x;
    const int wave = t >> 6, lane = t & 63;
    const int lm = lane & 15, lq = lane >> 4;
    const int wrow = (wave >> 1) * 64, wcol = (wave & 1) * 64;
    const int m0 = blockIdx.x * 128, n0 = blockIdx.y * 128;

    floatx4 acc[4][4] = {};

    for (int k0 = 0; k0 < K; k0 += 64) {
        __syncthreads();
#pragma unroll
        for (int rr = 0; rr < 4; rr++) {
            int p = rr * 256 + t;
            int row = p >> 3, g = p & 7;
            short8 va = *(const short8*)(Abf + (size_t)(m0 + row) * K + k0 + g * 8);
            const float* pw = W + (size_t)(n0 + row) * K + k0 + g * 8;
            floatx4 w0 = *(const floatx4*)pw, w1 = *(const floatx4*)(pw + 4);
            short8 vb;
#pragma unroll
            for (int d = 0; d < 4; d++) {
                vb[d]     = (short)f2bf(w0[d]);
                vb[4 + d] = (short)f2bf(w1[d]);
            }
            int dst = row * 8 + (g ^ (row & 7));
            *(short8*)(As + dst * 8) = va;
            *(short8*)(Bs + dst * 8) = vb;
        }
        __syncthreads();

        short8 af[4][2], bf[4][2];
#pragma unroll
        for (int i = 0; i < 4; i++)
#pragma unroll
            for (int c = 0; c < 2; c++) {
                int ra = wrow + i * 16 + lm;
                int rb = wcol + i * 16 + lm;
                int g = c * 4 + lq;
                af[i][c] = *(const short8*)(As + (ra * 8 + (g ^ (ra & 7))) * 8);
                bf[i][c] = *(const short8*)(Bs + (rb * 8 + (g ^ (rb & 7))) * 8);
            }
#pragma unroll
        for (int i = 0; i < 4; i++)
#pragma unroll
            for (int j = 0; j < 4; j++)
#pragma unroll
                for (int c = 0; c < 2; c++)
                    acc[i][j] = __builtin_amdgcn_mfma_f32_16x16x32_bf16(
                        af[i][c], bf[j][c], acc[i][j], 0, 0, 0);
    }

#pragma unroll
    for (int i = 0; i < 4; i++)
#pragma unroll
        for (int j = 0; j < 4; j++)
#pragma unroll
            for (int r = 0; r < 4; r++) {
                int gm = m0 + wrow + i * 16 + lq * 4 + r;
                int gn = n0 + wcol + j * 16 + lm;
                Out[(size_t)gm * D_MODEL + gn] = acc[i][j][r];
            }
}

extern "C" void kernel_launch(void* const* d_in, const int* in_sizes, int n_in,
                              void* d_out, int out_size, void* d_ws, size_t ws_size,
                              hipStream_t stream) {
    const float* x  = (const float*)d_in[0];
    const float* wq = (const float*)d_in[1];
    const float* wk = (const float*)d_in[2];
    const float* wv = (const float*)d_in[3];
    const float* wo = (const float*)d_in[4];

    unsigned short* ws = (unsigned short*)d_ws;
    const bool fast = ws_size >= (size_t)36 * 1024 * 1024 * 2;  // 72 MiB

    if (fast) {
        unsigned short* xbf  = ws;                     // 8M elems; reused as Ob
        unsigned short* wqkv = ws + (size_t)ELEMS;     // 3M
        unsigned short* wobf = ws + (size_t)ELEMS + 3 * WELEMS;  // 1M
        unsigned short* Qb   = ws + (size_t)ELEMS + 4 * WELEMS;  // 8M
        unsigned short* Kb   = Qb + ELEMS;
        unsigned short* Vb   = Kb + ELEMS;
        unsigned short* Ob   = xbf;                    // x_bf dead after QKV GEMM

        cvt_kernel<<<6144, 256, 0, stream>>>(x, wq, wk, wv, wo, xbf, wqkv, wobf);
        gemm_qkv2_kernel<<<dim3(64, 12), 256, 0, stream>>>(xbf, wqkv, Qb, Kb, Vb);
        attn4_kernel<<<dim3(16, BATCH * NH), 256, 0, stream>>>(Qb, Kb, Vb, Ob);
        row2047_kernel<<<BATCH * NH, 256, 0, stream>>>(Vb, Ob);
        gemm_out2_kernel<<<dim3(64, 4), 256, 0, stream>>>(Ob, wobf, (float*)d_out);
    } else {
        unsigned short* Qb = ws;
        unsigned short* Kb = Qb + ELEMS;
        unsigned short* Vb = Kb + ELEMS;
        unsigned short* Ob = Vb + ELEMS;

        gemm_qkv_kernel<<<dim3(64, 8, 3), 256, 0, stream>>>(x, wq, wk, wv, Qb, Kb, Vb);
        attn4_kernel<<<dim3(16, BATCH * NH), 256, 0, stream>>>(Qb, Kb, Vb, Ob);
        row2047_kernel<<<BATCH * NH, 256, 0, stream>>>(Vb, Ob);
        gemm_out_kernel<<<dim3(64, 8), 256, 0, stream>>>(Ob, wo, (float*)d_out);
    }
}

// Round 8
// 315.496 us; speedup vs baseline: 2.7394x; 2.4994x over previous
//
#include <hip/hip_runtime.h>
#include <hip/hip_bf16.h>

typedef __attribute__((ext_vector_type(8))) short short8;
typedef __attribute__((ext_vector_type(4))) short bfx4;
typedef __attribute__((ext_vector_type(4))) float floatx4;
typedef __attribute__((ext_vector_type(4))) __fp16 h4_t;
typedef __attribute__((ext_vector_type(2))) __fp16 h2_t;
typedef __attribute__((ext_vector_type(8))) __fp16 h8_t;

#define BATCH 4
#define SEQ 2048
#define D_MODEL 1024
#define NH 16
#define HD 64
#define ELEMS 8388608   // B*S*D = 4*2048*1024
#define WELEMS 1048576  // 1024*1024

// fp32 -> bf16 round-to-nearest-even
__device__ __forceinline__ unsigned short f2bf(float f) {
    union { float f; unsigned u; } x; x.f = f;
    unsigned r = x.u + 0x7FFFu + ((x.u >> 16) & 1u);
    return (unsigned short)(r >> 16);
}
__device__ __forceinline__ unsigned short f2h(float f) {
    union { __fp16 h; unsigned short u; } x;
    x.h = (__fp16)f;
    return x.u;
}

#if __has_builtin(__builtin_amdgcn_exp2f)
__device__ __forceinline__ float fexp2(float x) { return __builtin_amdgcn_exp2f(x); }
#else
__device__ __forceinline__ float fexp2(float x) { return exp2f(x); }
#endif

// async global->LDS, 16B per lane; HW dest = wave-uniform base + lane*16
__device__ __forceinline__ void gll16(const void* g, const void* l) {
    __builtin_amdgcn_global_load_lds(
        (const __attribute__((address_space(1))) void*)g,
        (__attribute__((address_space(3))) void*)l,
        16, 0, 0);
}

// ---------------------------------------------------------------------------
// cvt: x (8M), wq|wk|wv (3M, concatenated), wo (1M) fp32 -> bf16
// ---------------------------------------------------------------------------
__global__ __launch_bounds__(256)
void cvt_kernel(const float* __restrict__ x,  const float* __restrict__ wq,
                const float* __restrict__ wk, const float* __restrict__ wv,
                const float* __restrict__ wo,
                unsigned short* __restrict__ xbf,
                unsigned short* __restrict__ wqkv,
                unsigned short* __restrict__ wobf)
{
    size_t idx = ((size_t)blockIdx.x * 256 + threadIdx.x) * 8;
    const float* src; unsigned short* dst; size_t off;
    if (idx < (size_t)ELEMS)                    { src = x;  dst = xbf;             off = idx; }
    else if (idx < (size_t)ELEMS + WELEMS)      { src = wq; dst = wqkv;            off = idx - ELEMS; }
    else if (idx < (size_t)ELEMS + 2 * WELEMS)  { src = wk; dst = wqkv + WELEMS;   off = idx - ELEMS - WELEMS; }
    else if (idx < (size_t)ELEMS + 3 * WELEMS)  { src = wv; dst = wqkv + 2*WELEMS; off = idx - ELEMS - 2*WELEMS; }
    else                                        { src = wo; dst = wobf;            off = idx - ELEMS - 3*WELEMS; }
    floatx4 a = *(const floatx4*)(src + off);
    floatx4 b = *(const floatx4*)(src + off + 4);
    short8 v;
#pragma unroll
    for (int d = 0; d < 4; d++) { v[d] = (short)f2bf(a[d]); v[4+d] = (short)f2bf(b[d]); }
    *(short8*)(dst + off) = v;
}

// ---------------------------------------------------------------------------
// Fast QKV GEMM: A=x_bf [8192,1024], B=wqkv_bf [3072,1024] (NT), both staged
// via global_load_lds with inverse-XOR-swizzled source addressing.
// 128x256 tile, BK=64. Epilogue scatters Q/K/V (z uniform per block).
// ---------------------------------------------------------------------------
__global__ __launch_bounds__(256, 2)
void gemm_qkv2_kernel(const unsigned short* __restrict__ A,
                      const unsigned short* __restrict__ B,
                      unsigned short* __restrict__ Qb,
                      unsigned short* __restrict__ Kb,
                      unsigned short* __restrict__ Vb)
{
    __shared__ __align__(16) unsigned short As[128 * 64];
    __shared__ __align__(16) unsigned short Bs[256 * 64];

    const int t = threadIdx.x;
    const int wave = t >> 6, lane = t & 63;
    const int lm = lane & 15, lq = lane >> 4;
    const int wrow = (wave >> 1) * 64, wcol = (wave & 1) * 128;
    const int m0 = blockIdx.x * 128, n0 = blockIdx.y * 256;
    const int lrow = lane >> 3, lg = lane & 7;
    const int gsw = lg ^ lrow;

    floatx4 acc[4][8] = {};

    for (int k0 = 0; k0 < 1024; k0 += 64) {
        __syncthreads();
#pragma unroll
        for (int i = 0; i < 4; i++) {
            int rows8 = wave * 32 + i * 8;
            gll16(A + (size_t)(m0 + rows8 + lrow) * 1024 + k0 + gsw * 8, As + rows8 * 64);
        }
#pragma unroll
        for (int i = 0; i < 8; i++) {
            int rows8 = wave * 64 + i * 8;
            gll16(B + (size_t)(n0 + rows8 + lrow) * 1024 + k0 + gsw * 8, Bs + rows8 * 64);
        }
        __syncthreads();

#pragma unroll
        for (int c = 0; c < 2; c++) {
            short8 af[4], bfr[8];
#pragma unroll
            for (int i = 0; i < 4; i++) {
                int ra = wrow + i * 16 + lm;
                int g = c * 4 + lq;
                af[i] = *(const short8*)(As + (ra * 8 + (g ^ (ra & 7))) * 8);
            }
#pragma unroll
            for (int j = 0; j < 8; j++) {
                int rb = wcol + j * 16 + lm;
                int g = c * 4 + lq;
                bfr[j] = *(const short8*)(Bs + (rb * 8 + (g ^ (rb & 7))) * 8);
            }
#pragma unroll
            for (int i = 0; i < 4; i++)
#pragma unroll
                for (int j = 0; j < 8; j++)
                    acc[i][j] = __builtin_amdgcn_mfma_f32_16x16x32_bf16(
                        af[i], bfr[j], acc[i][j], 0, 0, 0);
        }
    }

    const int z = n0 >> 10;   // 0=Q 1=K 2=V, uniform per block
#pragma unroll
    for (int i = 0; i < 4; i++)
#pragma unroll
        for (int j = 0; j < 8; j++)
#pragma unroll
            for (int r = 0; r < 4; r++) {
                int gm = m0 + wrow + i * 16 + lq * 4 + r;
                int gn = n0 + wcol + j * 16 + lm;
                int nl = gn & 1023, h = nl >> 6, d = nl & 63;
                int b = gm >> 11, s = gm & 2047;
                float v = acc[i][j][r];
                size_t bh = (size_t)(b * NH + h);
                if (z == 0)      Qb[(bh * SEQ + s) * HD + d] = f2bf(v);
                else if (z == 1) Kb[(bh * SEQ + s) * HD + d] = f2bf(v);
                else             Vb[(bh * HD + d) * SEQ + s] = f2h(v);
            }
}

// ---------------------------------------------------------------------------
// Fast output projection: A=Ob bf16 [8192,1024], B=wo_bf [1024,1024] -> fp32
// ---------------------------------------------------------------------------
__global__ __launch_bounds__(256, 2)
void gemm_out2_kernel(const unsigned short* __restrict__ A,
                      const unsigned short* __restrict__ B,
                      float* __restrict__ Out)
{
    __shared__ __align__(16) unsigned short As[128 * 64];
    __shared__ __align__(16) unsigned short Bs[256 * 64];

    const int t = threadIdx.x;
    const int wave = t >> 6, lane = t & 63;
    const int lm = lane & 15, lq = lane >> 4;
    const int wrow = (wave >> 1) * 64, wcol = (wave & 1) * 128;
    const int m0 = blockIdx.x * 128, n0 = blockIdx.y * 256;
    const int lrow = lane >> 3, lg = lane & 7;
    const int gsw = lg ^ lrow;

    floatx4 acc[4][8] = {};

    for (int k0 = 0; k0 < 1024; k0 += 64) {
        __syncthreads();
#pragma unroll
        for (int i = 0; i < 4; i++) {
            int rows8 = wave * 32 + i * 8;
            gll16(A + (size_t)(m0 + rows8 + lrow) * 1024 + k0 + gsw * 8, As + rows8 * 64);
        }
#pragma unroll
        for (int i = 0; i < 8; i++) {
            int rows8 = wave * 64 + i * 8;
            gll16(B + (size_t)(n0 + rows8 + lrow) * 1024 + k0 + gsw * 8, Bs + rows8 * 64);
        }
        __syncthreads();

#pragma unroll
        for (int c = 0; c < 2; c++) {
            short8 af[4], bfr[8];
#pragma unroll
            for (int i = 0; i < 4; i++) {
                int ra = wrow + i * 16 + lm;
                int g = c * 4 + lq;
                af[i] = *(const short8*)(As + (ra * 8 + (g ^ (ra & 7))) * 8);
            }
#pragma unroll
            for (int j = 0; j < 8; j++) {
                int rb = wcol + j * 16 + lm;
                int g = c * 4 + lq;
                bfr[j] = *(const short8*)(Bs + (rb * 8 + (g ^ (rb & 7))) * 8);
            }
#pragma unroll
            for (int i = 0; i < 4; i++)
#pragma unroll
                for (int j = 0; j < 8; j++)
                    acc[i][j] = __builtin_amdgcn_mfma_f32_16x16x32_bf16(
                        af[i], bfr[j], acc[i][j], 0, 0, 0);
        }
    }

#pragma unroll
    for (int i = 0; i < 4; i++)
#pragma unroll
        for (int j = 0; j < 8; j++)
#pragma unroll
            for (int r = 0; r < 4; r++) {
                int gm = m0 + wrow + i * 16 + lq * 4 + r;
                int gn = n0 + wcol + j * 16 + lm;
                Out[(size_t)gm * D_MODEL + gn] = acc[i][j][r];
            }
}

// ---------------------------------------------------------------------------
// Flash attention v5: same algorithm as v4 (balanced paired q-tiles (j,31-j),
// no-max softmax, streamed sub-tiles) but __launch_bounds__(256, 2): the
// (256,4) bound pinned the allocator at 64 VGPRs and spilled both
// accumulator sets to scratch (R6/R7: 1.1 GB WRITE_SIZE, 588 us). The
// (256,2) bound (as used by the spill-free 84-VGPR GEMM kernels) lets the
// ~90 live VGPRs stay in registers. LDS 32 KB still allows 5 blocks/CU.
// Q,K bf16 [b,h,s,d]; V f16 [b,h,d,s]; O bf16 [b,s,1024].
// Row 2047 (l=0) fixed by row2047_kernel afterwards.
// ---------------------------------------------------------------------------
#define PROCESS_Q(QI, BQ, ACC, LACC, DOMASK, KT)                               \
    do {                                                                       \
        _Pragma("unroll")                                                      \
        for (int jt = 0; jt < 8; jt++) {                                       \
            floatx4 sc = {};                                                   \
            _Pragma("unroll")                                                  \
            for (int c = 0; c < 2; c++) {                                      \
                int row_ = jt * 16 + lm;                                       \
                int g_ = c * 4 + lq;                                           \
                short8 kf = *(const short8*)(Ks + (row_ * 8 + (g_ ^ (row_ & 7))) * 8); \
                sc = __builtin_amdgcn_mfma_f32_16x16x32_bf16(kf, BQ[c], sc, 0, 0, 0); \
            }                                                                  \
            if (DOMASK) {                                                      \
                _Pragma("unroll")                                              \
                for (int r = 0; r < 4; r++) {                                  \
                    int kj = (KT) * 128 + jt * 16 + lq * 4 + r;                \
                    if (!(kj > (QI))) sc[r] = -3.2e10f;                        \
                }                                                              \
            }                                                                  \
            float p0 = fexp2(sc[0] * kA), p1 = fexp2(sc[1] * kA);              \
            float p2 = fexp2(sc[2] * kA), p3 = fexp2(sc[3] * kA);              \
            LACC += (p0 + p1) + (p2 + p3);                                     \
            h2_t a01 = __builtin_amdgcn_cvt_pkrtz(p0, p1);                     \
            h2_t a23 = __builtin_amdgcn_cvt_pkrtz(p2, p3);                     \
            h4_t pf;                                                           \
            pf[0] = a01[0]; pf[1] = a01[1]; pf[2] = a23[0]; pf[3] = a23[1];    \
            _Pragma("unroll")                                                  \
            for (int jd = 0; jd < 4; jd++) {                                   \
                int rowv_ = jd * 16 + lm;                                      \
                int g16_ = jt * 2 + (lq >> 1);                                 \
                int slot_ = rowv_ * 16 + (g16_ ^ lm);                          \
                h4_t vf = *(const h4_t*)((const __fp16*)Vs + slot_ * 8 + (lq & 1) * 4); \
                ACC[jd] = __builtin_amdgcn_mfma_f32_16x16x16f16(vf, pf, ACC[jd], 0, 0, 0); \
            }                                                                  \
        }                                                                      \
    } while (0)

__global__ __launch_bounds__(256, 2)
void attn5_kernel(const unsigned short* __restrict__ Q,
                  const unsigned short* __restrict__ K,
                  const unsigned short* __restrict__ V,
                  unsigned short* __restrict__ O)
{
    __shared__ __align__(16) unsigned short Ks[128 * 64];  // [key][d] swizzled bf16
    __shared__ __align__(16) unsigned short Vs[64 * 128];  // [d][key] swizzled f16

    const int t = threadIdx.x;
    const int wave = t >> 6, lane = t & 63;
    const int lm = lane & 15, lq = lane >> 4;
    const int bh = blockIdx.y;
    const int jlo = blockIdx.x, jhi = 31 - jlo;
    const int qlo = jlo * 64 + wave * 16 + lm;
    const int qhi = jhi * 64 + wave * 16 + lm;

    const unsigned short* Qh = Q + (size_t)bh * SEQ * HD;
    const unsigned short* Kh = K + (size_t)bh * SEQ * HD;
    const unsigned short* Vh = V + (size_t)bh * HD * SEQ;  // [d][s]

    short8 bq_lo[2], bq_hi[2];
    bq_lo[0] = *(const short8*)(Qh + (size_t)qlo * HD + lq * 8);
    bq_lo[1] = *(const short8*)(Qh + (size_t)qlo * HD + 32 + lq * 8);
    bq_hi[0] = *(const short8*)(Qh + (size_t)qhi * HD + lq * 8);
    bq_hi[1] = *(const short8*)(Qh + (size_t)qhi * HD + 32 + lq * 8);

    floatx4 acc_lo[4] = {}, acc_hi[4] = {};
    float l_lo = 0.f, l_hi = 0.f;
    const float kA = 0.04508422002778011f;  // log2(e)/32

    const int lrow = lane >> 3, lg = lane & 7;
    const int kt_min = jlo >> 1;
    const int kthi_min = 15 - kt_min;

    for (int kt = 15; kt >= kt_min; kt--) {
        __syncthreads();
        // K tile: 128 keys x 64 d
#pragma unroll
        for (int i = 0; i < 4; i++) {
            int rows8 = wave * 32 + i * 8;
            gll16(Kh + (size_t)(kt * 128 + rows8 + lrow) * HD + (lg ^ lrow) * 8,
                  Ks + rows8 * 64);
        }
        // V^T tile: 64 d x 128 keys
#pragma unroll
        for (int i = 0; i < 4; i++) {
            int rows4 = wave * 16 + i * 4;
            int row = rows4 + (lane >> 4);
            int g = (lane & 15) ^ (row & 15);
            gll16(Vh + (size_t)row * SEQ + kt * 128 + g * 8, Vs + rows4 * 128);
        }
        __syncthreads();

        PROCESS_Q(qlo, bq_lo, acc_lo, l_lo, (kt == kt_min), kt);
        if (kt >= kthi_min)
            PROCESS_Q(qhi, bq_hi, acc_hi, l_hi, (kt == kthi_min), kt);
    }

    const int b = bh >> 4, h = bh & 15;
    {
        float l = l_lo;
        l += __shfl_xor(l, 16); l += __shfl_xor(l, 32);
        float inv = 1.0f / l;
#pragma unroll
        for (int jd = 0; jd < 4; jd++) {
            bfx4 o;
#pragma unroll
            for (int r = 0; r < 4; r++) o[r] = (short)f2bf(acc_lo[jd][r] * inv);
            *(bfx4*)(O + (size_t)(b * SEQ + qlo) * D_MODEL + h * HD + jd * 16 + lq * 4) = o;
        }
    }
    {
        float l = l_hi;
        l += __shfl_xor(l, 16); l += __shfl_xor(l, 32);
        float inv = 1.0f / l;
#pragma unroll
        for (int jd = 0; jd < 4; jd++) {
            bfx4 o;
#pragma unroll
            for (int r = 0; r < 4; r++) o[r] = (short)f2bf(acc_hi[jd][r] * inv);
            *(bfx4*)(O + (size_t)(b * SEQ + qhi) * D_MODEL + h * HD + jd * 16 + lq * 4) = o;
        }
    }
}

// ---------------------------------------------------------------------------
// Row 2047 is fully masked -> uniform softmax over ALL keys -> mean of V.
// ---------------------------------------------------------------------------
__global__ __launch_bounds__(256, 2)
void row2047_kernel(const unsigned short* __restrict__ V,
                    unsigned short* __restrict__ O)
{
    __shared__ float red[256];
    const int bh = blockIdx.x;
    const int b = bh >> 4, h = bh & 15;
    const int t = threadIdx.x;
    const int d = t & 63, seg = t >> 6;
    const __fp16* Vh = (const __fp16*)V + (size_t)bh * HD * SEQ + (size_t)d * SEQ + seg * 512;
    float s = 0.f;
    for (int i = 0; i < 512; i += 8) {
        h8_t v = *(const h8_t*)(Vh + i);
#pragma unroll
        for (int j = 0; j < 8; j++) s += (float)v[j];
    }
    red[t] = s;
    __syncthreads();
    if (seg == 0) {
        float tot = red[d] + red[64 + d] + red[128 + d] + red[192 + d];
        O[(size_t)(b * SEQ + 2047) * D_MODEL + h * HD + d] = f2bf(tot * (1.f / 2048.f));
    }
}

// ======================= fallback (ws < 72 MiB) kernels =====================
__global__ __launch_bounds__(256, 2)
void gemm_qkv_kernel(const float* __restrict__ A,
                     const float* __restrict__ W0,
                     const float* __restrict__ W1,
                     const float* __restrict__ W2,
                     unsigned short* __restrict__ O0,
                     unsigned short* __restrict__ O1,
                     unsigned short* __restrict__ O2)
{
    const int K = 1024;
    const float* W;
    unsigned short* Out;
    if (blockIdx.z == 0)      { W = W0; Out = O0; }
    else if (blockIdx.z == 1) { W = W1; Out = O1; }
    else                      { W = W2; Out = O2; }

    __shared__ __align__(16) unsigned short As[128 * 64];
    __shared__ __align__(16) unsigned short Bs[128 * 64];

    const int t = threadIdx.x;
    const int wave = t >> 6, lane = t & 63;
    const int lm = lane & 15, lq = lane >> 4;
    const int wrow = (wave >> 1) * 64, wcol = (wave & 1) * 64;
    const int m0 = blockIdx.x * 128, n0 = blockIdx.y * 128;

    floatx4 acc[4][4] = {};

    for (int k0 = 0; k0 < K; k0 += 64) {
        __syncthreads();
#pragma unroll
        for (int rr = 0; rr < 4; rr++) {
            int p = rr * 256 + t;
            int row = p >> 3, g = p & 7;
            const float* pa = A + (size_t)(m0 + row) * K + k0 + g * 8;
            const float* pw = W + (size_t)(n0 + row) * K + k0 + g * 8;
            floatx4 a0 = *(const floatx4*)pa, a1 = *(const floatx4*)(pa + 4);
            floatx4 w0 = *(const floatx4*)pw, w1 = *(const floatx4*)(pw + 4);
            short8 va, vb;
#pragma unroll
            for (int d = 0; d < 4; d++) {
                va[d]     = (short)f2bf(a0[d]);
                va[4 + d] = (short)f2bf(a1[d]);
                vb[d]     = (short)f2bf(w0[d]);
                vb[4 + d] = (short)f2bf(w1[d]);
            }
            int dst = row * 8 + (g ^ (row & 7));
            *(short8*)(As + dst * 8) = va;
            *(short8*)(Bs + dst * 8) = vb;
        }
        __syncthreads();

        short8 af[4][2], bf[4][2];
#pragma unroll
        for (int i = 0; i < 4; i++)
#pragma unroll
            for (int c = 0; c < 2; c++) {
                int ra = wrow + i * 16 + lm;
                int rb = wcol + i * 16 + lm;
                int g = c * 4 + lq;
                af[i][c] = *(const short8*)(As + (ra * 8 + (g ^ (ra & 7))) * 8);
                bf[i][c] = *(const short8*)(Bs + (rb * 8 + (g ^ (rb & 7))) * 8);
            }
#pragma unroll
        for (int i = 0; i < 4; i++)
#pragma unroll
            for (int j = 0; j < 4; j++)
#pragma unroll
                for (int c = 0; c < 2; c++)
                    acc[i][j] = __builtin_amdgcn_mfma_f32_16x16x32_bf16(
                        af[i][c], bf[j][c], acc[i][j], 0, 0, 0);
    }

    const int zi = blockIdx.z;
#pragma unroll
    for (int i = 0; i < 4; i++)
#pragma unroll
        for (int j = 0; j < 4; j++)
#pragma unroll
            for (int r = 0; r < 4; r++) {
                int gm = m0 + wrow + i * 16 + lq * 4 + r;
                int gn = n0 + wcol + j * 16 + lm;
                int b = gm >> 11, s = gm & 2047;
                int h = gn >> 6, d = gn & 63;
                if (zi == 2) {
                    Out[((size_t)(b * NH + h) * HD + d) * SEQ + s] = f2h(acc[i][j][r]);
                } else {
                    Out[((size_t)(b * NH + h) * SEQ + s) * HD + d] = f2bf(acc[i][j][r]);
                }
            }
}

__global__ __launch_bounds__(256, 2)
void gemm_out_kernel(const unsigned short* __restrict__ Abf,
                     const float* __restrict__ W,
                     float* __restrict__ Out)
{
    const int K = 1024;
    __shared__ __align__(16) unsigned short As[128 * 64];
    __shared__ __align__(16) unsigned short Bs[128 * 64];

    const int t = threadIdx.x;
    const int wave = t >> 6, lane = t & 63;
    const int lm = lane & 15, lq = lane >> 4;
    const int wrow = (wave >> 1) * 64, wcol = (wave & 1) * 64;
    const int m0 = blockIdx.x * 128, n0 = blockIdx.y * 128;

    floatx4 acc[4][4] = {};

    for (int k0 = 0; k0 < K; k0 += 64) {
        __syncthreads();
#pragma unroll
        for (int rr = 0; rr < 4; rr++) {
            int p = rr * 256 + t;
            int row = p >> 3, g = p & 7;
            short8 va = *(const short8*)(Abf + (size_t)(m0 + row) * K + k0 + g * 8);
            const float* pw = W + (size_t)(n0 + row) * K + k0 + g * 8;
            floatx4 w0 = *(const floatx4*)pw, w1 = *(const floatx4*)(pw + 4);
            short8 vb;
#pragma unroll
            for (int d = 0; d < 4; d++) {
                vb[d]     = (short)f2bf(w0[d]);
                vb[4 + d] = (short)f2bf(w1[d]);
            }
            int dst = row * 8 + (g ^ (row & 7));
            *(short8*)(As + dst * 8) = va;
            *(short8*)(Bs + dst * 8) = vb;
        }
        __syncthreads();

        short8 af[4][2], bf[4][2];
#pragma unroll
        for (int i = 0; i < 4; i++)
#pragma unroll
            for (int c = 0; c < 2; c++) {
                int ra = wrow + i * 16 + lm;
                int rb = wcol + i * 16 + lm;
                int g = c * 4 + lq;
                af[i][c] = *(const short8*)(As + (ra * 8 + (g ^ (ra & 7))) * 8);
                bf[i][c] = *(const short8*)(Bs + (rb * 8 + (g ^ (rb & 7))) * 8);
            }
#pragma unroll
        for (int i = 0; i < 4; i++)
#pragma unroll
            for (int j = 0; j < 4; j++)
#pragma unroll
                for (int c = 0; c < 2; c++)
                    acc[i][j] = __builtin_amdgcn_mfma_f32_16x16x32_bf16(
                        af[i][c], bf[j][c], acc[i][j], 0, 0, 0);
    }

#pragma unroll
    for (int i = 0; i < 4; i++)
#pragma unroll
        for (int j = 0; j < 4; j++)
#pragma unroll
            for (int r = 0; r < 4; r++) {
                int gm = m0 + wrow + i * 16 + lq * 4 + r;
                int gn = n0 + wcol + j * 16 + lm;
                Out[(size_t)gm * D_MODEL + gn] = acc[i][j][r];
            }
}

extern "C" void kernel_launch(void* const* d_in, const int* in_sizes, int n_in,
                              void* d_out, int out_size, void* d_ws, size_t ws_size,
                              hipStream_t stream) {
    const float* x  = (const float*)d_in[0];
    const float* wq = (const float*)d_in[1];
    const float* wk = (const float*)d_in[2];
    const float* wv = (const float*)d_in[3];
    const float* wo = (const float*)d_in[4];

    unsigned short* ws = (unsigned short*)d_ws;
    const bool fast = ws_size >= (size_t)36 * 1024 * 1024 * 2;  // 72 MiB

    if (fast) {
        unsigned short* xbf  = ws;                     // 8M elems; reused as Ob
        unsigned short* wqkv = ws + (size_t)ELEMS;     // 3M
        unsigned short* wobf = ws + (size_t)ELEMS + 3 * WELEMS;  // 1M
        unsigned short* Qb   = ws + (size_t)ELEMS + 4 * WELEMS;  // 8M
        unsigned short* Kb   = Qb + ELEMS;
        unsigned short* Vb   = Kb + ELEMS;
        unsigned short* Ob   = xbf;                    // x_bf dead after QKV GEMM

        cvt_kernel<<<6144, 256, 0, stream>>>(x, wq, wk, wv, wo, xbf, wqkv, wobf);
        gemm_qkv2_kernel<<<dim3(64, 12), 256, 0, stream>>>(xbf, wqkv, Qb, Kb, Vb);
        attn5_kernel<<<dim3(16, BATCH * NH), 256, 0, stream>>>(Qb, Kb, Vb, Ob);
        row2047_kernel<<<BATCH * NH, 256, 0, stream>>>(Vb, Ob);
        gemm_out2_kernel<<<dim3(64, 4), 256, 0, stream>>>(Ob, wobf, (float*)d_out);
    } else {
        unsigned short* Qb = ws;
        unsigned short* Kb = Qb + ELEMS;
        unsigned short* Vb = Kb + ELEMS;
        unsigned short* Ob = Vb + ELEMS;

        gemm_qkv_kernel<<<dim3(64, 8, 3), 256, 0, stream>>>(x, wq, wk, wv, Qb, Kb, Vb);
        attn5_kernel<<<dim3(16, BATCH * NH), 256, 0, stream>>>(Qb, Kb, Vb, Ob);
        row2047_kernel<<<BATCH * NH, 256, 0, stream>>>(Vb, Ob);
        gemm_out_kernel<<<dim3(64, 8), 256, 0, stream>>>(Ob, wo, (float*)d_out);
    }
}